// Round 4
// baseline (92.662 us; speedup 1.0000x reference)
//
#include <hip/hip_runtime.h>

#define VDIM   32
#define NPAIR  496              // 32*31/2
#define NBASIS 14               // DEG + ORDER - 1
#define NPARAM (NBASIS * NPAIR) // 6944
#define ROWS   16               // rows per block
#define BLK    512              // threads per block (2 row-groups x 256)
#define SPS    15               // pair-major param stride (odd -> bank spread)

typedef float f32x4 __attribute__((ext_vector_type(4)));

// u = (x - t0)/dist with t0 = LO - 3*dist, dist = 30/11.  -t0/dist == 8.5 exactly.
__device__ __forceinline__ float spline_u(float xi) {
    const float invd = 11.0f / 30.0f;
    float x = fminf(fmaxf(xi, -15.0f), 15.0f - 1e-6f);
    return x * invd + 8.5f;
}

// 1024 blocks x 512 threads (32 waves/CU): params pair-major in LDS (only LDS
// user, 29 KB -> 4 blocks/CU at full 2048-thread residency). x read from
// global (L1 broadcast), spline weights recomputed in registers.
__global__ __launch_bounds__(BLK, 8) void Decorrelation_35270271435435_kernel(
    const float* __restrict__ input,    // [N,32]
    const float* __restrict__ params,   // [14,496] k-major
    float* __restrict__ out,            // [N,32]
    float* __restrict__ lm,             // [N,32,32]
    float* __restrict__ pens,           // [3]
    int N)
{
    __shared__ float sp[NPAIR * SPS];        // 29.0 KB pair-major params
    __shared__ float wsum[3][8];

    const int tid = threadIdx.x;
    const int n0  = blockIdx.x * ROWS;

    // ---- Stage params into LDS, transposed to pair-major stride-15 ----
    {
        const f32x4* p4 = (const f32x4*)params;
        for (int i4 = tid; i4 < NPARAM / 4; i4 += BLK) {
            const f32x4 val = p4[i4];        // coalesced global read
            const int base = i4 * 4;
            #pragma unroll
            for (int e = 0; e < 4; ++e) {
                const int idx = base + e;
                const int k = idx / NPAIR;   // magic-mul, setup only
                const int p = idx - k * NPAIR;
                sp[p * SPS + k] = val[e];    // stride-15 scatter: conflict-light
            }
        }
    }
    __syncthreads();

    // ---- Per-thread constants (row-invariant) ----
    const int g  = tid >> 8;          // row-parity group (0/1)
    const int v  = (tid >> 3) & 31;   // lm row this thread serves
    const int t  = tid & 7;
    const int c0 = t << 2;            // first of 4 consecutive cols
    int  pb[4];
    bool low[4], dia[4];
    #pragma unroll
    for (int j = 0; j < 4; ++j) {
        const int c = c0 + j;
        low[j] = (c < v);
        dia[j] = (c == v);
        pb[j]  = ((v * (v - 1)) / 2 + c) * SPS;   // tril_indices(-1) flat order
    }

    // rows r = g, g+2, ..., g+14 ; store slot = (v*32 + c0)
    float* lmp0 = lm + (size_t)(n0 + g) * (VDIM * VDIM) + (tid & 255) * 4;

    #pragma unroll 2
    for (int i = 0; i < ROWS / 2; ++i) {
        const int r = g + (i << 1);
        const int n = n0 + r;
        if (n >= N) break;
        // raw x for this row's 4 cols: 16B global load, L1-broadcast across v
        const f32x4 x4 = *(const f32x4*)&input[(size_t)n * VDIM + c0];
        float vals[4];
        float partial = 0.0f;
        #pragma unroll
        for (int j = 0; j < 4; ++j) {
            float val = 0.0f;
            if (dia[j]) {
                val = 1.0f;
            } else if (low[j]) {
                const float u = spline_u(x4[j]);
                float fi = floorf(u);
                fi = fminf(fmaxf(fi, 3.0f), 13.0f);
                const float uu  = u - fi;
                const float om  = 1.0f - uu;
                const float uu2 = uu * uu, uu3 = uu2 * uu;
                const float sixth = 1.0f / 6.0f;
                const float w0 = om * om * om * sixth;
                const float w1 = (3.0f * uu3 - 6.0f * uu2 + 4.0f) * sixth;
                const float w2 = (-3.0f * uu3 + 3.0f * uu2 + 3.0f * uu + 1.0f) * sixth;
                const float w3 = uu3 * sixth;
                const int k0 = (int)fi - 3;
                const float* q = &sp[pb[j] + k0];      // 4 contiguous taps
                val = w0 * q[0] + w1 * q[1] + w2 * q[2] + w3 * q[3];
            }
            vals[j] = val;
            partial += val * x4[j];
        }
        const f32x4 f4 = { vals[0], vals[1], vals[2], vals[3] };
        __builtin_nontemporal_store(f4, (f32x4*)(lmp0 + (size_t)(i << 1) * (VDIM * VDIM)));

        partial += __shfl_down(partial, 4, 8);
        partial += __shfl_down(partial, 2, 8);
        partial += __shfl_down(partial, 1, 8);
        if (t == 0) out[(size_t)n * VDIM + v] = partial;
    }

    // ---- Penalty scalars (block 0 only; pair-major chains, all static idx) ----
    if (blockIdx.x == 0) {
        float s2 = 0.0f, s1 = 0.0f, spn = 0.0f;
        for (int p = tid; p < NPAIR; p += BLK) {
            const float* q = &sp[p * SPS];
            float a[NBASIS];
            #pragma unroll
            for (int k = 0; k < NBASIS; ++k) { a[k] = q[k]; spn += a[k] * a[k]; }
            #pragma unroll
            for (int k = 0; k < NBASIS - 1; ++k) {
                const float d = a[k + 1] - a[k];
                s1 += d * d;
            }
            #pragma unroll
            for (int k = 0; k < NBASIS - 2; ++k) {
                const float d = a[k + 2] - 2.0f * a[k + 1] + a[k];
                s2 += d * d;
            }
        }
        #pragma unroll
        for (int off = 32; off > 0; off >>= 1) {
            s2  += __shfl_down(s2, off);
            s1  += __shfl_down(s1, off);
            spn += __shfl_down(spn, off);
        }
        const int lane = tid & 63, wid = tid >> 6;
        if (lane == 0) { wsum[0][wid] = s2; wsum[1][wid] = s1; wsum[2][wid] = spn; }
        __syncthreads();
        if (tid == 0) {
            float r0 = 0.f, r1 = 0.f, r2 = 0.f;
            #pragma unroll
            for (int w = 0; w < 8; ++w) { r0 += wsum[0][w]; r1 += wsum[1][w]; r2 += wsum[2][w]; }
            pens[0] = r0; pens[1] = r1; pens[2] = r2;
        }
    }
}

extern "C" void kernel_launch(void* const* d_in, const int* in_sizes, int n_in,
                              void* d_out, int out_size, void* d_ws, size_t ws_size,
                              hipStream_t stream) {
    const float* input  = (const float*)d_in[0];   // [N,32]
    // d_in[1] = log_d : unused by the reference
    const float* params = (const float*)d_in[2];   // [14,496]
    const int N = in_sizes[0] / VDIM;              // 16384

    float* out  = (float*)d_out;                   // [N,32]
    float* lm   = out + (size_t)N * VDIM;          // [N,32,32]
    float* pens = lm + (size_t)N * VDIM * VDIM;    // [3]

    const int nb = (N + ROWS - 1) / ROWS;          // 1024
    Decorrelation_35270271435435_kernel<<<nb, BLK, 0, stream>>>(
        input, params, out, lm, pens, N);
}